// Round 1
// 542.814 us; speedup vs baseline: 1.0883x; 1.0883x over previous
//
#include <hip/hip_runtime.h>
#include <hip/hip_bf16.h>

#define HW 192
#define HWHW 36864
#define NB 4

typedef __attribute__((ext_vector_type(8))) short short8;
typedef __attribute__((ext_vector_type(4))) float floatx4;

__device__ __forceinline__ unsigned pack_bf2(float a, float b) {
    __hip_bfloat162 h = __float22bfloat162_rn(make_float2(a, b));
    return *(unsigned*)&h;
}
__device__ __forceinline__ float4 ld_bf16x4(const __hip_bfloat16* p) {
    uint2 u = *(const uint2*)p;
    __hip_bfloat162 a = *(__hip_bfloat162*)&u.x;
    __hip_bfloat162 b = *(__hip_bfloat162*)&u.y;
    float2 fa = __bfloat1622float2(a), fb = __bfloat1622float2(b);
    return make_float4(fa.x, fa.y, fb.x, fb.y);
}
__device__ __forceinline__ void st_bf16x4(__hip_bfloat16* p, float4 v) {
    uint2 u;
    u.x = pack_bf2(v.x, v.y);
    u.y = pack_bf2(v.z, v.w);
    *(uint2*)p = u;
}

// ---------------- upflow ----------------
__global__ void upflow_kernel(const float* __restrict__ fin,
                              const float* __restrict__ w,
                              float* __restrict__ fout) {
    int idx = blockIdx.x * blockDim.x + threadIdx.x;
    if (idx >= NB * 2 * HWHW) return;
    int x = idx % HW;
    int y = (idx / HW) % HW;
    int g = (idx / HWHW) % 2;
    int b = idx / (2 * HWHW);
    float acc = 0.f;
#pragma unroll
    for (int ky = 0; ky < 4; ++ky) {
        int py = y + ky - 2;
        if (py < 0 || py > 190 || (py & 1)) continue;
        int iy = py >> 1;
#pragma unroll
        for (int kx = 0; kx < 4; ++kx) {
            int px = x + kx - 2;
            if (px < 0 || px > 190 || (px & 1)) continue;
            int ix = px >> 1;
            acc += fin[((b * 2 + g) * 96 + iy) * 96 + ix] *
                   w[g * 16 + (3 - ky) * 4 + (3 - kx)];
        }
    }
    fout[idx] = acc;
}

// ---------------- weight prep: fp32 [CO][CI][3][3] -> bf16 [9][CO][CIP] ----------------
__global__ void wprep_kernel(const float* __restrict__ w, __hip_bfloat16* __restrict__ out,
                             int CO, int CI, int CIP) {
    int idx = blockIdx.x * blockDim.x + threadIdx.x;
    int n = 9 * CO * CIP;
    if (idx >= n) return;
    int ci = idx % CIP;
    int co = (idx / CIP) % CO;
    int k9 = idx / (CIP * CO);
    float v = (ci < CI) ? w[(co * CI + ci) * 9 + k9] : 0.f;
    out[idx] = __float2bfloat16(v);
}

// ---------------- backwarp: px-thread x 4 channel-groups, NCHW fp32 -> NHWC96 bf16 ----------------
__global__ __launch_bounds__(256) void backwarp_kernel(const float* __restrict__ feat,
                                                       const float* __restrict__ flow,
                                                       __hip_bfloat16* __restrict__ out) {
    int p = blockIdx.x * blockDim.x + threadIdx.x;
    if (p >= NB * HWHW) return;
    int cg = blockIdx.y;  // channel group: 24 channels
    int x = p % HW;
    int y = (p / HW) % HW;
    int b = p / HWHW;
    float fx = flow[((b * 2 + 0) * HW + y) * HW + x] * 2.5f;
    float fy = flow[((b * 2 + 1) * HW + y) * HW + x] * 2.5f;
    float gx = (float)x + fx, gy = (float)y + fy;
    float x0f = floorf(gx), y0f = floorf(gy);
    float wx = gx - x0f, wy = gy - y0f;
    int x0 = (int)x0f, y0 = (int)y0f;
    bool xv0 = (unsigned)x0 < (unsigned)HW;
    bool xv1 = (unsigned)(x0 + 1) < (unsigned)HW;
    bool yv0 = (unsigned)y0 < (unsigned)HW;
    bool yv1 = (unsigned)(y0 + 1) < (unsigned)HW;
    float w00 = (1.f - wy) * (1.f - wx) * ((yv0 && xv0) ? 1.f : 0.f);
    float w01 = (1.f - wy) * wx * ((yv0 && xv1) ? 1.f : 0.f);
    float w10 = wy * (1.f - wx) * ((yv1 && xv0) ? 1.f : 0.f);
    float w11 = wy * wx * ((yv1 && xv1) ? 1.f : 0.f);
    int xc0 = min(max(x0, 0), HW - 1), xc1 = min(max(x0 + 1, 0), HW - 1);
    int yc0 = min(max(y0, 0), HW - 1), yc1 = min(max(y0 + 1, 0), HW - 1);
    const float* fb = feat + (size_t)b * 96 * HWHW + (size_t)cg * 24 * HWHW;
    int i00 = yc0 * HW + xc0, i01 = yc0 * HW + xc1;
    int i10 = yc1 * HW + xc0, i11 = yc1 * HW + xc1;
    __hip_bfloat16* op = out + (size_t)p * 96 + cg * 24;
#pragma unroll
    for (int c = 0; c < 24; c += 8) {
        float r[8];
#pragma unroll
        for (int j = 0; j < 8; ++j) {
            const float* fc = fb + (size_t)(c + j) * HWHW;
            r[j] = w00 * fc[i00] + w01 * fc[i01] + w10 * fc[i10] + w11 * fc[i11];
        }
        uint4 u;
        u.x = pack_bf2(r[0], r[1]);
        u.y = pack_bf2(r[2], r[3]);
        u.z = pack_bf2(r[4], r[5]);
        u.w = pack_bf2(r[6], r[7]);
        *(uint4*)&op[c] = u;
    }
}

// ---------------- correlation via banded-Gram MFMA ----------------
// Block: 4 waves, each owns one y-row of 16 px. For each dy in [-3,3], the 16x22
// Gram matrix between the f1 row (16 px) and the f2 row at y+dy (cols x0-3..x0+18)
// is computed as 2 N-tiles of mfma_f32_16x16x32_bf16 over 3 ci-chunks; the diagonal
// band dx = col-row in [0,6] is the correlation output. f1 is staged fp32->bf16
// hi/lo split (2 MFMAs) to keep fp32-level precision on the f1 operand.
#define CIS2 40  // halfword stride per px: 80B => 16B-aligned b128, ~2-way banks (free)
__global__ __launch_bounds__(256) void corr_mfma_kernel(const float* __restrict__ f1,
                                                        const __hip_bfloat16* __restrict__ f2,
                                                        __hip_bfloat16* __restrict__ out) {
    __shared__ __hip_bfloat16 s_f1h[4 * 16 * CIS2];
    __shared__ __hip_bfloat16 s_f1l[4 * 16 * CIS2];
    __shared__ __hip_bfloat16 s_f2[10 * 22 * CIS2];
    __shared__ float s_out[4][16][52];

    const int t = threadIdx.x;
    const int lane = t & 63;
    const int wave = t >> 6;   // y-row within block
    const int q = lane >> 4;
    const int l16 = lane & 15;
    const int x0 = blockIdx.x * 16;
    const int y0 = blockIdx.y * 4;
    const int b = blockIdx.z;

    floatx4 acc[7][2];
#pragma unroll
    for (int d = 0; d < 7; ++d)
#pragma unroll
        for (int nt = 0; nt < 2; ++nt) acc[d][nt] = (floatx4){0.f, 0.f, 0.f, 0.f};

    for (int ci0 = 0; ci0 < 96; ci0 += 32) {
        __syncthreads();
        // stage f1: 4 rows x 16 px x 32 ch, NCHW fp32 -> bf16 hi + lo residual, [row][px][ci]
        for (int idx = t; idx < 1024; idx += 256) {
            int px = idx & 15;
            int cp = (idx >> 4) & 15;   // channel pair
            int row = idx >> 8;
            const float* p = f1 + (size_t)(b * 96 + ci0 + cp * 2) * HWHW + (y0 + row) * HW + (x0 + px);
            float v0 = p[0], v1 = p[HWHW];
            float h0 = __bfloat162float(__float2bfloat16(v0));
            float h1 = __bfloat162float(__float2bfloat16(v1));
            int o = (row * 16 + px) * CIS2 + cp * 2;
            *(unsigned*)&s_f1h[o] = pack_bf2(v0, v1);
            *(unsigned*)&s_f1l[o] = pack_bf2(v0 - h0, v1 - h1);
        }
        // stage f2 slab: rows y0-3..y0+6 (10), cols x0-3..x0+18 (22), 32 ch, zero-fill OOB
        for (int idx = t; idx < 10 * 22 * 4; idx += 256) {
            int c16 = idx & 3;
            int c = (idx >> 2) % 22;
            int rr = idx / 88;
            int gy = y0 + rr - 3, gx = x0 + c - 3;
            uint4 u = make_uint4(0u, 0u, 0u, 0u);
            if ((unsigned)gy < (unsigned)HW && (unsigned)gx < (unsigned)HW)
                u = *(const uint4*)&f2[(size_t)((b * HW + gy) * HW + gx) * 96 + ci0 + c16 * 8];
            *(uint4*)&s_f2[(rr * 22 + c) * CIS2 + c16 * 8] = u;
        }
        __syncthreads();
        short8 Ah = *(const short8*)&s_f1h[(wave * 16 + l16) * CIS2 + q * 8];
        short8 Al = *(const short8*)&s_f1l[(wave * 16 + l16) * CIS2 + q * 8];
#pragma unroll
        for (int d = 0; d < 7; ++d) {
#pragma unroll
            for (int nt = 0; nt < 2; ++nt) {
                int col = nt * 16 + l16;
                col = col < 22 ? col : 21;  // lanes past the band read col 21 (discarded)
                short8 B = *(const short8*)&s_f2[((wave + d) * 22 + col) * CIS2 + q * 8];
                acc[d][nt] = __builtin_amdgcn_mfma_f32_16x16x32_bf16(Ah, B, acc[d][nt], 0, 0, 0);
                acc[d][nt] = __builtin_amdgcn_mfma_f32_16x16x32_bf16(Al, B, acc[d][nt], 0, 0, 0);
            }
        }
    }
    // extract band: D row (q*4+reg) = f1 px, col (nt*16+l16) = f2 col; dx = col-row
#pragma unroll
    for (int d = 0; d < 7; ++d)
#pragma unroll
        for (int nt = 0; nt < 2; ++nt)
#pragma unroll
            for (int reg = 0; reg < 4; ++reg) {
                int p1 = q * 4 + reg;
                int dx = nt * 16 + l16 - p1;
                if (dx >= 0 && dx < 7) s_out[wave][p1][d * 7 + dx] = acc[d][nt][reg];
            }
    __syncthreads();
    // coalesced NHWC64 bf16 write: /96 + leaky, ch 49..63 zero
    {
        int px = t >> 2;
        int row = px >> 4, xl = px & 15;
        int ch0 = (t & 3) * 16;
        int gy = y0 + row, gx = x0 + xl;
        float r[16];
#pragma unroll
        for (int j = 0; j < 16; ++j) {
            int ch = ch0 + j;
            float a = (ch < 49) ? s_out[row][xl][ch] * (1.0f / 96.0f) : 0.f;
            r[j] = a >= 0.f ? a : 0.1f * a;
        }
        __hip_bfloat16* op = out + (size_t)((b * HW + gy) * HW + gx) * 64 + ch0;
        uint4 u0, u1;
        u0.x = pack_bf2(r[0], r[1]);  u0.y = pack_bf2(r[2], r[3]);
        u0.z = pack_bf2(r[4], r[5]);  u0.w = pack_bf2(r[6], r[7]);
        u1.x = pack_bf2(r[8], r[9]);  u1.y = pack_bf2(r[10], r[11]);
        u1.z = pack_bf2(r[12], r[13]); u1.w = pack_bf2(r[14], r[15]);
        *(uint4*)op = u0;
        *(uint4*)(op + 8) = u1;
    }
}

// ---------------- MFMA implicit-GEMM 3x3 conv (m97-style 4x4 wave tile) ----------------
template <int CIN, int COUT, int WAVES_CO, int WCO, int LEAKY>
__global__ __launch_bounds__(256) void convk(const __hip_bfloat16* __restrict__ in,
                                             const __hip_bfloat16* __restrict__ wg,
                                             const float* __restrict__ bias,
                                             __hip_bfloat16* __restrict__ out) {
    constexpr int WAVES_PX = 4 / WAVES_CO;
    constexpr int BR = WAVES_PX * 4;          // block rows of pixels
    constexpr int CIS = 36;                   // padded ci stride (72B -> 16-bank spread)
    static_assert(WAVES_CO * WCO * 16 == COUT, "one co-block covers all COUT");
    __shared__ __hip_bfloat16 s_in[BR * 18 * CIS];
    __shared__ __hip_bfloat16 s_w[3 * COUT * CIS];

    const int t = threadIdx.x;
    const int lane = t & 63;
    const int wave = t >> 6;
    const int q = lane >> 4;
    const int l16 = lane & 15;
    const int wr = wave % WAVES_PX;           // px row-group
    const int wc = wave / WAVES_PX;           // co group
    const int x0 = blockIdx.x * 16;
    const int y0 = blockIdx.y * BR;
    const int b = blockIdx.z;

    floatx4 acc[4][WCO];
#pragma unroll
    for (int i = 0; i < 4; ++i)
#pragma unroll
        for (int j = 0; j < WCO; ++j) acc[i][j] = (floatx4){0.f, 0.f, 0.f, 0.f};

    for (int ci0 = 0; ci0 < CIN; ci0 += 32) {
#pragma unroll
        for (int ky = 0; ky < 3; ++ky) {
            __syncthreads();
            // stage input rows [y0+ky-1 .. +BR-1], cols [x0-1 .. x0+16], 32 ci
            for (int ch = t; ch < BR * 18 * 4; ch += 256) {
                int c8 = (ch & 3) * 8;
                int px = ch >> 2;
                int s = px / 18, cc = px % 18;
                int gy = y0 + s + ky - 1, gx = x0 + cc - 1;
                uint4 u = make_uint4(0u, 0u, 0u, 0u);
                if ((unsigned)gy < (unsigned)HW && (unsigned)gx < (unsigned)HW)
                    u = *(const uint4*)&in[(size_t)((b * HW + gy) * HW + gx) * CIN + ci0 + c8];
                *(uint4*)&s_in[(s * 18 + cc) * CIS + c8] = u;
            }
            // stage weights [kx 0..2][COUT][32ci]
            for (int ch = t; ch < 3 * COUT * 4; ch += 256) {
                int c8 = (ch & 3) * 8;
                int co = (ch >> 2) % COUT;
                int kx = ch / (COUT * 4);
                *(uint4*)&s_w[(kx * COUT + co) * CIS + c8] =
                    *(const uint4*)&wg[(size_t)((ky * 3 + kx) * COUT + co) * CIN + ci0 + c8];
            }
            __syncthreads();
#pragma unroll
            for (int kx = 0; kx < 3; ++kx) {
                short8 A[WCO], B[4];
#pragma unroll
                for (int ct = 0; ct < WCO; ++ct)
                    A[ct] = *(const short8*)&s_w[(kx * COUT + wc * WCO * 16 + ct * 16 + l16) * CIS + q * 8];
#pragma unroll
                for (int pt = 0; pt < 4; ++pt)
                    B[pt] = *(const short8*)&s_in[((wr * 4 + pt) * 18 + l16 + kx) * CIS + q * 8];
#pragma unroll
                for (int pt = 0; pt < 4; ++pt)
#pragma unroll
                    for (int ct = 0; ct < WCO; ++ct)
                        acc[pt][ct] = __builtin_amdgcn_mfma_f32_16x16x32_bf16(A[ct], B[pt], acc[pt][ct], 0, 0, 0);
            }
        }
    }
    // epilogue: D col(lane&15)=pixel col, row(q*4+reg)=co within tile
#pragma unroll
    for (int pt = 0; pt < 4; ++pt) {
        int y = y0 + wr * 4 + pt;
        int x = x0 + l16;
        size_t pixbase = (size_t)((b * HW + y) * HW + x) * COUT;
#pragma unroll
        for (int ct = 0; ct < WCO; ++ct) {
            int co4 = wc * WCO * 16 + ct * 16 + q * 4;
            float4 bv = *(const float4*)&bias[co4];
            float r[4];
#pragma unroll
            for (int reg = 0; reg < 4; ++reg) {
                float vv = acc[pt][ct][reg] + ((const float*)&bv)[reg];
                if (LEAKY) vv = vv >= 0.f ? vv : 0.1f * vv;
                r[reg] = vv;
            }
            uint2 u;
            u.x = pack_bf2(r[0], r[1]);
            u.y = pack_bf2(r[2], r[3]);
            *(uint2*)&out[pixbase + co4] = u;
        }
    }
}

// ---------------- conv4: 5x5, 32->2, pad 2, NHWC32 bf16 in, + bias + flow residual ----------------
__global__ __launch_bounds__(256) void conv4_kernel(const __hip_bfloat16* __restrict__ in,
                                                    const float* __restrict__ wg,
                                                    const float* __restrict__ bias,
                                                    const float* __restrict__ flow,
                                                    float* __restrict__ out) {
    __shared__ float s_in[20 * 20 * 36];
    __shared__ float s_w[2 * 25 * 32];
    int t = threadIdx.x;
    int tx = t % 16, ty = t / 16;
    int x0 = blockIdx.x * 16, y0 = blockIdx.y * 16, b = blockIdx.z;
    for (int ch = t; ch < 400 * 4; ch += 256) {
        int px = ch >> 2;
        int c8 = (ch & 3) * 8;
        int ry = px / 20, rx = px % 20;
        int gy = y0 + ry - 2, gx = x0 + rx - 2;
        float4 lo = make_float4(0.f, 0.f, 0.f, 0.f), hi = lo;
        if ((unsigned)gy < (unsigned)HW && (unsigned)gx < (unsigned)HW) {
            const __hip_bfloat16* p = &in[(size_t)((b * HW + gy) * HW + gx) * 32 + c8];
            lo = ld_bf16x4(p);
            hi = ld_bf16x4(p + 4);
        }
        *(float4*)&s_in[px * 36 + c8] = lo;
        *(float4*)&s_in[px * 36 + c8 + 4] = hi;
    }
    for (int p = t; p < 1600; p += 256) {
        int ci = p % 32;
        int k = (p / 32) % 25;
        int co = p / 800;
        s_w[(co * 25 + k) * 32 + ci] = wg[(co * 32 + ci) * 25 + k];
    }
    __syncthreads();
    float acc0 = 0.f, acc1 = 0.f;
#pragma unroll
    for (int ky = 0; ky < 5; ++ky) {
#pragma unroll
        for (int kx = 0; kx < 5; ++kx) {
            int k = ky * 5 + kx;
            int base = ((ty + ky) * 20 + tx + kx) * 36;
#pragma unroll
            for (int c4 = 0; c4 < 32; c4 += 4) {
                float4 v = *(const float4*)&s_in[base + c4];
                float4 w0 = *(const float4*)&s_w[(0 * 25 + k) * 32 + c4];
                float4 w1 = *(const float4*)&s_w[(1 * 25 + k) * 32 + c4];
                acc0 += v.x * w0.x + v.y * w0.y + v.z * w0.z + v.w * w0.w;
                acc1 += v.x * w1.x + v.y * w1.y + v.z * w1.z + v.w * w1.w;
            }
        }
    }
    int gy = y0 + ty, gx = x0 + tx;
    int o0 = ((b * 2 + 0) * HWHW) + gy * HW + gx;
    int o1 = ((b * 2 + 1) * HWHW) + gy * HW + gx;
    out[o0] = acc0 + bias[0] + flow[o0];
    out[o1] = acc1 + bias[1] + flow[o1];
}

extern "C" void kernel_launch(void* const* d_in, const int* in_sizes, int n_in,
                              void* d_out, int out_size, void* d_ws, size_t ws_size,
                              hipStream_t stream) {
    (void)in_sizes; (void)n_in; (void)out_size; (void)ws_size;
    const float* f1      = (const float*)d_in[2];
    const float* f2in    = (const float*)d_in[3];
    const float* flow_in = (const float*)d_in[4];
    const float* w_up    = (const float*)d_in[5];
    const float* w1      = (const float*)d_in[6];
    const float* b1      = (const float*)d_in[7];
    const float* w2      = (const float*)d_in[8];
    const float* b2      = (const float*)d_in[9];
    const float* w3      = (const float*)d_in[10];
    const float* b3      = (const float*)d_in[11];
    const float* w4      = (const float*)d_in[12];
    const float* b4      = (const float*)d_in[13];
    float* out = (float*)d_out;
    char* ws = (char*)d_ws;

    // ws layout: flow fp32 [0,1179648) | w1b [1179648) | w2b [1327104) | w3b [1474560)
    //   R1 (feat2 NHWC96 / x1 NHWC128) [1511424, +37748736)
    //   R2 (corr/x2 NHWC64) [39260160, +18874368) | R3 (x3 NHWC32) [58134528, +9437184)
    float* flow = (float*)ws;
    __hip_bfloat16* w1b = (__hip_bfloat16*)(ws + 1179648);
    __hip_bfloat16* w2b = (__hip_bfloat16*)(ws + 1327104);
    __hip_bfloat16* w3b = (__hip_bfloat16*)(ws + 1474560);
    __hip_bfloat16* R1  = (__hip_bfloat16*)(ws + 1511424);
    __hip_bfloat16* R2  = (__hip_bfloat16*)(ws + 39260160);
    __hip_bfloat16* R3  = (__hip_bfloat16*)(ws + 58134528);

    upflow_kernel<<<1152, 256, 0, stream>>>(flow_in, w_up, flow);
    wprep_kernel<<<288, 256, 0, stream>>>(w1, w1b, 128, 49, 64);
    wprep_kernel<<<288, 256, 0, stream>>>(w2, w2b, 64, 128, 128);
    wprep_kernel<<<72, 256, 0, stream>>>(w3, w3b, 32, 64, 64);
    backwarp_kernel<<<dim3(576, 4), 256, 0, stream>>>(f2in, flow, R1);
    corr_mfma_kernel<<<dim3(12, 48, NB), 256, 0, stream>>>(f1, R1, R2);
    convk<64, 128, 2, 4, 1><<<dim3(12, 24, NB), 256, 0, stream>>>(R2, w1b, b1, R1);
    convk<128, 64, 1, 4, 1><<<dim3(12, 12, NB), 256, 0, stream>>>(R1, w2b, b2, R2);
    convk<64, 32, 1, 2, 1><<<dim3(12, 12, NB), 256, 0, stream>>>(R2, w3b, b3, R3);
    conv4_kernel<<<dim3(12, 12, NB), 256, 0, stream>>>(R3, w4, b4, flow, out);
}

// Round 2
// 531.532 us; speedup vs baseline: 1.1114x; 1.0212x over previous
//
#include <hip/hip_runtime.h>
#include <hip/hip_bf16.h>

#define HW 192
#define HWHW 36864
#define NB 4

typedef __attribute__((ext_vector_type(8))) short short8;
typedef __attribute__((ext_vector_type(4))) float floatx4;

__device__ __forceinline__ unsigned pack_bf2(float a, float b) {
    __hip_bfloat162 h = __float22bfloat162_rn(make_float2(a, b));
    return *(unsigned*)&h;
}
__device__ __forceinline__ float4 ld_bf16x4(const __hip_bfloat16* p) {
    uint2 u = *(const uint2*)p;
    __hip_bfloat162 a = *(__hip_bfloat162*)&u.x;
    __hip_bfloat162 b = *(__hip_bfloat162*)&u.y;
    float2 fa = __bfloat1622float2(a), fb = __bfloat1622float2(b);
    return make_float4(fa.x, fa.y, fb.x, fb.y);
}
__device__ __forceinline__ void st_bf16x4(__hip_bfloat16* p, float4 v) {
    uint2 u;
    u.x = pack_bf2(v.x, v.y);
    u.y = pack_bf2(v.z, v.w);
    *(uint2*)p = u;
}

// ---------------- upflow ----------------
__global__ void upflow_kernel(const float* __restrict__ fin,
                              const float* __restrict__ w,
                              float* __restrict__ fout) {
    int idx = blockIdx.x * blockDim.x + threadIdx.x;
    if (idx >= NB * 2 * HWHW) return;
    int x = idx % HW;
    int y = (idx / HW) % HW;
    int g = (idx / HWHW) % 2;
    int b = idx / (2 * HWHW);
    float acc = 0.f;
#pragma unroll
    for (int ky = 0; ky < 4; ++ky) {
        int py = y + ky - 2;
        if (py < 0 || py > 190 || (py & 1)) continue;
        int iy = py >> 1;
#pragma unroll
        for (int kx = 0; kx < 4; ++kx) {
            int px = x + kx - 2;
            if (px < 0 || px > 190 || (px & 1)) continue;
            int ix = px >> 1;
            acc += fin[((b * 2 + g) * 96 + iy) * 96 + ix] *
                   w[g * 16 + (3 - ky) * 4 + (3 - kx)];
        }
    }
    fout[idx] = acc;
}

// ---------------- weight prep: fp32 [CO][CI][3][3] -> bf16 [9][CO][CIP] ----------------
__global__ void wprep_kernel(const float* __restrict__ w, __hip_bfloat16* __restrict__ out,
                             int CO, int CI, int CIP) {
    int idx = blockIdx.x * blockDim.x + threadIdx.x;
    int n = 9 * CO * CIP;
    if (idx >= n) return;
    int ci = idx % CIP;
    int co = (idx / CIP) % CO;
    int k9 = idx / (CIP * CO);
    float v = (ci < CI) ? w[(co * CI + ci) * 9 + k9] : 0.f;
    out[idx] = __float2bfloat16(v);
}

// ---------------- backwarp: lane = (pixel, cg) so each wave writes 16 full pixels ----------------
// NCHW fp32 gather -> NHWC96 bf16. lane%4 = channel group (24 ch). A wave covers 16
// consecutive pixels -> 3072 contiguous output bytes, all 64B sectors fully covered
// within one wave on one XCD (no cross-XCD partial-sector RMW).
__global__ __launch_bounds__(256) void backwarp_kernel(const float* __restrict__ feat,
                                                       const float* __restrict__ flow,
                                                       __hip_bfloat16* __restrict__ out) {
    int g = blockIdx.x * blockDim.x + threadIdx.x;
    int cg = g & 3;
    int p = g >> 2;
    if (p >= NB * HWHW) return;
    int x = p % HW;
    int y = (p / HW) % HW;
    int b = p / HWHW;
    float fx = flow[((b * 2 + 0) * HW + y) * HW + x] * 2.5f;
    float fy = flow[((b * 2 + 1) * HW + y) * HW + x] * 2.5f;
    float gx = (float)x + fx, gy = (float)y + fy;
    float x0f = floorf(gx), y0f = floorf(gy);
    float wx = gx - x0f, wy = gy - y0f;
    int x0 = (int)x0f, y0 = (int)y0f;
    bool xv0 = (unsigned)x0 < (unsigned)HW;
    bool xv1 = (unsigned)(x0 + 1) < (unsigned)HW;
    bool yv0 = (unsigned)y0 < (unsigned)HW;
    bool yv1 = (unsigned)(y0 + 1) < (unsigned)HW;
    float w00 = (1.f - wy) * (1.f - wx) * ((yv0 && xv0) ? 1.f : 0.f);
    float w01 = (1.f - wy) * wx * ((yv0 && xv1) ? 1.f : 0.f);
    float w10 = wy * (1.f - wx) * ((yv1 && xv0) ? 1.f : 0.f);
    float w11 = wy * wx * ((yv1 && xv1) ? 1.f : 0.f);
    int xc0 = min(max(x0, 0), HW - 1), xc1 = min(max(x0 + 1, 0), HW - 1);
    int yc0 = min(max(y0, 0), HW - 1), yc1 = min(max(y0 + 1, 0), HW - 1);
    const float* fb = feat + (size_t)b * 96 * HWHW + (size_t)cg * 24 * HWHW;
    int i00 = yc0 * HW + xc0, i01 = yc0 * HW + xc1;
    int i10 = yc1 * HW + xc0, i11 = yc1 * HW + xc1;
    __hip_bfloat16* op = out + (size_t)p * 96 + cg * 24;
#pragma unroll
    for (int c = 0; c < 24; c += 8) {
        float r[8];
#pragma unroll
        for (int j = 0; j < 8; ++j) {
            const float* fc = fb + (size_t)(c + j) * HWHW;
            r[j] = w00 * fc[i00] + w01 * fc[i01] + w10 * fc[i10] + w11 * fc[i11];
        }
        uint4 u;
        u.x = pack_bf2(r[0], r[1]);
        u.y = pack_bf2(r[2], r[3]);
        u.z = pack_bf2(r[4], r[5]);
        u.w = pack_bf2(r[6], r[7]);
        *(uint4*)&op[c] = u;
    }
}

// ---------------- correlation via banded-Gram MFMA ----------------
#define CIS2 40  // halfword stride per px: 80B => 16B-aligned b128, ~2-way banks (free)
__global__ __launch_bounds__(256) void corr_mfma_kernel(const float* __restrict__ f1,
                                                        const __hip_bfloat16* __restrict__ f2,
                                                        __hip_bfloat16* __restrict__ out) {
    __shared__ __hip_bfloat16 s_f1h[4 * 16 * CIS2];
    __shared__ __hip_bfloat16 s_f1l[4 * 16 * CIS2];
    __shared__ __hip_bfloat16 s_f2[10 * 22 * CIS2];
    __shared__ float s_out[4][16][52];

    const int t = threadIdx.x;
    const int lane = t & 63;
    const int wave = t >> 6;   // y-row within block
    const int q = lane >> 4;
    const int l16 = lane & 15;
    const int x0 = blockIdx.x * 16;
    const int y0 = blockIdx.y * 4;
    const int b = blockIdx.z;

    floatx4 acc[7][2];
#pragma unroll
    for (int d = 0; d < 7; ++d)
#pragma unroll
        for (int nt = 0; nt < 2; ++nt) acc[d][nt] = (floatx4){0.f, 0.f, 0.f, 0.f};

    for (int ci0 = 0; ci0 < 96; ci0 += 32) {
        __syncthreads();
        // stage f1: 4 rows x 16 px x 32 ch, NCHW fp32 -> bf16 hi + lo residual, [row][px][ci]
        for (int idx = t; idx < 1024; idx += 256) {
            int px = idx & 15;
            int cp = (idx >> 4) & 15;   // channel pair
            int row = idx >> 8;
            const float* p = f1 + (size_t)(b * 96 + ci0 + cp * 2) * HWHW + (y0 + row) * HW + (x0 + px);
            float v0 = p[0], v1 = p[HWHW];
            float h0 = __bfloat162float(__float2bfloat16(v0));
            float h1 = __bfloat162float(__float2bfloat16(v1));
            int o = (row * 16 + px) * CIS2 + cp * 2;
            *(unsigned*)&s_f1h[o] = pack_bf2(v0, v1);
            *(unsigned*)&s_f1l[o] = pack_bf2(v0 - h0, v1 - h1);
        }
        // stage f2 slab: rows y0-3..y0+6 (10), cols x0-3..x0+18 (22), 32 ch, zero-fill OOB
        for (int idx = t; idx < 10 * 22 * 4; idx += 256) {
            int c16 = idx & 3;
            int c = (idx >> 2) % 22;
            int rr = idx / 88;
            int gy = y0 + rr - 3, gx = x0 + c - 3;
            uint4 u = make_uint4(0u, 0u, 0u, 0u);
            if ((unsigned)gy < (unsigned)HW && (unsigned)gx < (unsigned)HW)
                u = *(const uint4*)&f2[(size_t)((b * HW + gy) * HW + gx) * 96 + ci0 + c16 * 8];
            *(uint4*)&s_f2[(rr * 22 + c) * CIS2 + c16 * 8] = u;
        }
        __syncthreads();
        short8 Ah = *(const short8*)&s_f1h[(wave * 16 + l16) * CIS2 + q * 8];
        short8 Al = *(const short8*)&s_f1l[(wave * 16 + l16) * CIS2 + q * 8];
#pragma unroll
        for (int d = 0; d < 7; ++d) {
#pragma unroll
            for (int nt = 0; nt < 2; ++nt) {
                int col = nt * 16 + l16;
                col = col < 22 ? col : 21;  // lanes past the band read col 21 (discarded)
                short8 B = *(const short8*)&s_f2[((wave + d) * 22 + col) * CIS2 + q * 8];
                acc[d][nt] = __builtin_amdgcn_mfma_f32_16x16x32_bf16(Ah, B, acc[d][nt], 0, 0, 0);
                acc[d][nt] = __builtin_amdgcn_mfma_f32_16x16x32_bf16(Al, B, acc[d][nt], 0, 0, 0);
            }
        }
    }
    // extract band: D row (q*4+reg) = f1 px, col (nt*16+l16) = f2 col; dx = col-row
#pragma unroll
    for (int d = 0; d < 7; ++d)
#pragma unroll
        for (int nt = 0; nt < 2; ++nt)
#pragma unroll
            for (int reg = 0; reg < 4; ++reg) {
                int p1 = q * 4 + reg;
                int dx = nt * 16 + l16 - p1;
                if (dx >= 0 && dx < 7) s_out[wave][p1][d * 7 + dx] = acc[d][nt][reg];
            }
    __syncthreads();
    // coalesced NHWC64 bf16 write: /96 + leaky, ch 49..63 zero
    {
        int px = t >> 2;
        int row = px >> 4, xl = px & 15;
        int ch0 = (t & 3) * 16;
        int gy = y0 + row, gx = x0 + xl;
        float r[16];
#pragma unroll
        for (int j = 0; j < 16; ++j) {
            int ch = ch0 + j;
            float a = (ch < 49) ? s_out[row][xl][ch] * (1.0f / 96.0f) : 0.f;
            r[j] = a >= 0.f ? a : 0.1f * a;
        }
        __hip_bfloat16* op = out + (size_t)((b * HW + gy) * HW + gx) * 64 + ch0;
        uint4 u0, u1;
        u0.x = pack_bf2(r[0], r[1]);  u0.y = pack_bf2(r[2], r[3]);
        u0.z = pack_bf2(r[4], r[5]);  u0.w = pack_bf2(r[6], r[7]);
        u1.x = pack_bf2(r[8], r[9]);  u1.y = pack_bf2(r[10], r[11]);
        u1.z = pack_bf2(r[12], r[13]); u1.w = pack_bf2(r[14], r[15]);
        *(uint4*)op = u0;
        *(uint4*)(op + 8) = u1;
    }
}

// ---------------- MFMA implicit-GEMM 3x3 conv (m97-style 4x4 wave tile) ----------------
template <int CIN, int COUT, int WAVES_CO, int WCO, int LEAKY>
__global__ __launch_bounds__(256) void convk(const __hip_bfloat16* __restrict__ in,
                                             const __hip_bfloat16* __restrict__ wg,
                                             const float* __restrict__ bias,
                                             __hip_bfloat16* __restrict__ out) {
    constexpr int WAVES_PX = 4 / WAVES_CO;
    constexpr int BR = WAVES_PX * 4;          // block rows of pixels
    constexpr int CIS = 36;                   // padded ci stride (72B -> 16-bank spread)
    static_assert(WAVES_CO * WCO * 16 == COUT, "one co-block covers all COUT");
    __shared__ __hip_bfloat16 s_in[BR * 18 * CIS];
    __shared__ __hip_bfloat16 s_w[3 * COUT * CIS];

    const int t = threadIdx.x;
    const int lane = t & 63;
    const int wave = t >> 6;
    const int q = lane >> 4;
    const int l16 = lane & 15;
    const int wr = wave % WAVES_PX;           // px row-group
    const int wc = wave / WAVES_PX;           // co group
    const int x0 = blockIdx.x * 16;
    const int y0 = blockIdx.y * BR;
    const int b = blockIdx.z;

    floatx4 acc[4][WCO];
#pragma unroll
    for (int i = 0; i < 4; ++i)
#pragma unroll
        for (int j = 0; j < WCO; ++j) acc[i][j] = (floatx4){0.f, 0.f, 0.f, 0.f};

    for (int ci0 = 0; ci0 < CIN; ci0 += 32) {
#pragma unroll
        for (int ky = 0; ky < 3; ++ky) {
            __syncthreads();
            // stage input rows [y0+ky-1 .. +BR-1], cols [x0-1 .. x0+16], 32 ci
            for (int ch = t; ch < BR * 18 * 4; ch += 256) {
                int c8 = (ch & 3) * 8;
                int px = ch >> 2;
                int s = px / 18, cc = px % 18;
                int gy = y0 + s + ky - 1, gx = x0 + cc - 1;
                uint4 u = make_uint4(0u, 0u, 0u, 0u);
                if ((unsigned)gy < (unsigned)HW && (unsigned)gx < (unsigned)HW)
                    u = *(const uint4*)&in[(size_t)((b * HW + gy) * HW + gx) * CIN + ci0 + c8];
                *(uint4*)&s_in[(s * 18 + cc) * CIS + c8] = u;
            }
            // stage weights [kx 0..2][COUT][32ci]
            for (int ch = t; ch < 3 * COUT * 4; ch += 256) {
                int c8 = (ch & 3) * 8;
                int co = (ch >> 2) % COUT;
                int kx = ch / (COUT * 4);
                *(uint4*)&s_w[(kx * COUT + co) * CIS + c8] =
                    *(const uint4*)&wg[(size_t)((ky * 3 + kx) * COUT + co) * CIN + ci0 + c8];
            }
            __syncthreads();
#pragma unroll
            for (int kx = 0; kx < 3; ++kx) {
                short8 A[WCO], B[4];
#pragma unroll
                for (int ct = 0; ct < WCO; ++ct)
                    A[ct] = *(const short8*)&s_w[(kx * COUT + wc * WCO * 16 + ct * 16 + l16) * CIS + q * 8];
#pragma unroll
                for (int pt = 0; pt < 4; ++pt)
                    B[pt] = *(const short8*)&s_in[((wr * 4 + pt) * 18 + l16 + kx) * CIS + q * 8];
#pragma unroll
                for (int pt = 0; pt < 4; ++pt)
#pragma unroll
                    for (int ct = 0; ct < WCO; ++ct)
                        acc[pt][ct] = __builtin_amdgcn_mfma_f32_16x16x32_bf16(A[ct], B[pt], acc[pt][ct], 0, 0, 0);
            }
        }
    }
    // epilogue: D col(lane&15)=pixel col, row(q*4+reg)=co within tile
#pragma unroll
    for (int pt = 0; pt < 4; ++pt) {
        int y = y0 + wr * 4 + pt;
        int x = x0 + l16;
        size_t pixbase = (size_t)((b * HW + y) * HW + x) * COUT;
#pragma unroll
        for (int ct = 0; ct < WCO; ++ct) {
            int co4 = wc * WCO * 16 + ct * 16 + q * 4;
            float4 bv = *(const float4*)&bias[co4];
            float r[4];
#pragma unroll
            for (int reg = 0; reg < 4; ++reg) {
                float vv = acc[pt][ct][reg] + ((const float*)&bv)[reg];
                if (LEAKY) vv = vv >= 0.f ? vv : 0.1f * vv;
                r[reg] = vv;
            }
            uint2 u;
            u.x = pack_bf2(r[0], r[1]);
            u.y = pack_bf2(r[2], r[3]);
            *(uint2*)&out[pixbase + co4] = u;
        }
    }
}

// ---------------- conv4: 5x5, 32->2, pad 2, NHWC32 bf16 in, + bias + flow residual ----------------
__global__ __launch_bounds__(256) void conv4_kernel(const __hip_bfloat16* __restrict__ in,
                                                    const float* __restrict__ wg,
                                                    const float* __restrict__ bias,
                                                    const float* __restrict__ flow,
                                                    float* __restrict__ out) {
    __shared__ float s_in[20 * 20 * 36];
    __shared__ float s_w[2 * 25 * 32];
    int t = threadIdx.x;
    int tx = t % 16, ty = t / 16;
    int x0 = blockIdx.x * 16, y0 = blockIdx.y * 16, b = blockIdx.z;
    for (int ch = t; ch < 400 * 4; ch += 256) {
        int px = ch >> 2;
        int c8 = (ch & 3) * 8;
        int ry = px / 20, rx = px % 20;
        int gy = y0 + ry - 2, gx = x0 + rx - 2;
        float4 lo = make_float4(0.f, 0.f, 0.f, 0.f), hi = lo;
        if ((unsigned)gy < (unsigned)HW && (unsigned)gx < (unsigned)HW) {
            const __hip_bfloat16* p = &in[(size_t)((b * HW + gy) * HW + gx) * 32 + c8];
            lo = ld_bf16x4(p);
            hi = ld_bf16x4(p + 4);
        }
        *(float4*)&s_in[px * 36 + c8] = lo;
        *(float4*)&s_in[px * 36 + c8 + 4] = hi;
    }
    for (int p = t; p < 1600; p += 256) {
        int ci = p % 32;
        int k = (p / 32) % 25;
        int co = p / 800;
        s_w[(co * 25 + k) * 32 + ci] = wg[(co * 32 + ci) * 25 + k];
    }
    __syncthreads();
    float acc0 = 0.f, acc1 = 0.f;
#pragma unroll
    for (int ky = 0; ky < 5; ++ky) {
#pragma unroll
        for (int kx = 0; kx < 5; ++kx) {
            int k = ky * 5 + kx;
            int base = ((ty + ky) * 20 + tx + kx) * 36;
#pragma unroll
            for (int c4 = 0; c4 < 32; c4 += 4) {
                float4 v = *(const float4*)&s_in[base + c4];
                float4 w0 = *(const float4*)&s_w[(0 * 25 + k) * 32 + c4];
                float4 w1 = *(const float4*)&s_w[(1 * 25 + k) * 32 + c4];
                acc0 += v.x * w0.x + v.y * w0.y + v.z * w0.z + v.w * w0.w;
                acc1 += v.x * w1.x + v.y * w1.y + v.z * w1.z + v.w * w1.w;
            }
        }
    }
    int gy = y0 + ty, gx = x0 + tx;
    int o0 = ((b * 2 + 0) * HWHW) + gy * HW + gx;
    int o1 = ((b * 2 + 1) * HWHW) + gy * HW + gx;
    out[o0] = acc0 + bias[0] + flow[o0];
    out[o1] = acc1 + bias[1] + flow[o1];
}

extern "C" void kernel_launch(void* const* d_in, const int* in_sizes, int n_in,
                              void* d_out, int out_size, void* d_ws, size_t ws_size,
                              hipStream_t stream) {
    (void)in_sizes; (void)n_in; (void)out_size; (void)ws_size;
    const float* f1      = (const float*)d_in[2];
    const float* f2in    = (const float*)d_in[3];
    const float* flow_in = (const float*)d_in[4];
    const float* w_up    = (const float*)d_in[5];
    const float* w1      = (const float*)d_in[6];
    const float* b1      = (const float*)d_in[7];
    const float* w2      = (const float*)d_in[8];
    const float* b2      = (const float*)d_in[9];
    const float* w3      = (const float*)d_in[10];
    const float* b3      = (const float*)d_in[11];
    const float* w4      = (const float*)d_in[12];
    const float* b4      = (const float*)d_in[13];
    float* out = (float*)d_out;
    char* ws = (char*)d_ws;

    // ws layout: flow fp32 [0,1179648) | w1b [1179648) | w2b [1327104) | w3b [1474560)
    //   R1 (feat2 NHWC96 / x1 NHWC128) [1511424, +37748736)
    //   R2 (corr/x2 NHWC64) [39260160, +18874368) | R3 (x3 NHWC32) [58134528, +9437184)
    float* flow = (float*)ws;
    __hip_bfloat16* w1b = (__hip_bfloat16*)(ws + 1179648);
    __hip_bfloat16* w2b = (__hip_bfloat16*)(ws + 1327104);
    __hip_bfloat16* w3b = (__hip_bfloat16*)(ws + 1474560);
    __hip_bfloat16* R1  = (__hip_bfloat16*)(ws + 1511424);
    __hip_bfloat16* R2  = (__hip_bfloat16*)(ws + 39260160);
    __hip_bfloat16* R3  = (__hip_bfloat16*)(ws + 58134528);

    upflow_kernel<<<1152, 256, 0, stream>>>(flow_in, w_up, flow);
    wprep_kernel<<<288, 256, 0, stream>>>(w1, w1b, 128, 49, 64);
    wprep_kernel<<<288, 256, 0, stream>>>(w2, w2b, 64, 128, 128);
    wprep_kernel<<<72, 256, 0, stream>>>(w3, w3b, 32, 64, 64);
    backwarp_kernel<<<2304, 256, 0, stream>>>(f2in, flow, R1);
    corr_mfma_kernel<<<dim3(12, 48, NB), 256, 0, stream>>>(f1, R1, R2);
    convk<64, 128, 2, 4, 1><<<dim3(12, 24, NB), 256, 0, stream>>>(R2, w1b, b1, R1);
    convk<128, 64, 1, 4, 1><<<dim3(12, 12, NB), 256, 0, stream>>>(R1, w2b, b2, R2);
    convk<64, 32, 1, 2, 1><<<dim3(12, 12, NB), 256, 0, stream>>>(R2, w3b, b3, R3);
    conv4_kernel<<<dim3(12, 12, NB), 256, 0, stream>>>(R3, w4, b4, flow, out);
}

// Round 3
// 521.408 us; speedup vs baseline: 1.1330x; 1.0194x over previous
//
#include <hip/hip_runtime.h>
#include <hip/hip_bf16.h>

#define HW 192
#define HWHW 36864
#define NB 4

typedef __attribute__((ext_vector_type(8))) short short8;
typedef __attribute__((ext_vector_type(4))) float floatx4;

__device__ __forceinline__ unsigned pack_bf2(float a, float b) {
    __hip_bfloat162 h = __float22bfloat162_rn(make_float2(a, b));
    return *(unsigned*)&h;
}
__device__ __forceinline__ float4 ld_bf16x4(const __hip_bfloat16* p) {
    uint2 u = *(const uint2*)p;
    __hip_bfloat162 a = *(__hip_bfloat162*)&u.x;
    __hip_bfloat162 b = *(__hip_bfloat162*)&u.y;
    float2 fa = __bfloat1622float2(a), fb = __bfloat1622float2(b);
    return make_float4(fa.x, fa.y, fb.x, fb.y);
}
__device__ __forceinline__ void st_bf16x4(__hip_bfloat16* p, float4 v) {
    uint2 u;
    u.x = pack_bf2(v.x, v.y);
    u.y = pack_bf2(v.z, v.w);
    *(uint2*)p = u;
}

// ---------------- upflow ----------------
__global__ void upflow_kernel(const float* __restrict__ fin,
                              const float* __restrict__ w,
                              float* __restrict__ fout) {
    int idx = blockIdx.x * blockDim.x + threadIdx.x;
    if (idx >= NB * 2 * HWHW) return;
    int x = idx % HW;
    int y = (idx / HW) % HW;
    int g = (idx / HWHW) % 2;
    int b = idx / (2 * HWHW);
    float acc = 0.f;
#pragma unroll
    for (int ky = 0; ky < 4; ++ky) {
        int py = y + ky - 2;
        if (py < 0 || py > 190 || (py & 1)) continue;
        int iy = py >> 1;
#pragma unroll
        for (int kx = 0; kx < 4; ++kx) {
            int px = x + kx - 2;
            if (px < 0 || px > 190 || (px & 1)) continue;
            int ix = px >> 1;
            acc += fin[((b * 2 + g) * 96 + iy) * 96 + ix] *
                   w[g * 16 + (3 - ky) * 4 + (3 - kx)];
        }
    }
    fout[idx] = acc;
}

// ---------------- weight prep: fp32 [CO][CI][3][3] -> bf16 [9][CO][CIP] ----------------
__global__ void wprep_kernel(const float* __restrict__ w, __hip_bfloat16* __restrict__ out,
                             int CO, int CI, int CIP) {
    int idx = blockIdx.x * blockDim.x + threadIdx.x;
    int n = 9 * CO * CIP;
    if (idx >= n) return;
    int ci = idx % CIP;
    int co = (idx / CIP) % CO;
    int k9 = idx / (CIP * CO);
    float v = (ci < CI) ? w[(co * CI + ci) * 9 + k9] : 0.f;
    out[idx] = __float2bfloat16(v);
}

// ---------------- backwarp: XCD-chunked swizzle + LDS-transposed coalesced writeback ----------------
// lane = (pixel, cg); block = 64 consecutive pixels. XCD k owns contiguous block range
// [k*288, (k+1)*288) so neighboring row-blocks share feat rows in the same per-XCD L2.
// Output tile staged in LDS, written back as 3 x 4096B fully-covered block stores
// (no partial-sector write-allocate RMW).
__global__ __launch_bounds__(256) void backwarp_kernel(const float* __restrict__ feat,
                                                       const float* __restrict__ flow,
                                                       __hip_bfloat16* __restrict__ out) {
    __shared__ uint4 s_t[768];
    int bid = blockIdx.x;
    int blk = (bid & 7) * 288 + (bid >> 3);   // 2304 blocks, 288 per XCD, bijective
    int t = threadIdx.x;
    int cg = t & 3;
    int pl = t >> 2;                           // local pixel 0..63
    int p = blk * 64 + pl;
    int x = p % HW;
    int y = (p / HW) % HW;
    int b = p / HWHW;
    float fx = flow[((b * 2 + 0) * HW + y) * HW + x] * 2.5f;
    float fy = flow[((b * 2 + 1) * HW + y) * HW + x] * 2.5f;
    float gx = (float)x + fx, gy = (float)y + fy;
    float x0f = floorf(gx), y0f = floorf(gy);
    float wx = gx - x0f, wy = gy - y0f;
    int x0 = (int)x0f, y0 = (int)y0f;
    bool xv0 = (unsigned)x0 < (unsigned)HW;
    bool xv1 = (unsigned)(x0 + 1) < (unsigned)HW;
    bool yv0 = (unsigned)y0 < (unsigned)HW;
    bool yv1 = (unsigned)(y0 + 1) < (unsigned)HW;
    float w00 = (1.f - wy) * (1.f - wx) * ((yv0 && xv0) ? 1.f : 0.f);
    float w01 = (1.f - wy) * wx * ((yv0 && xv1) ? 1.f : 0.f);
    float w10 = wy * (1.f - wx) * ((yv1 && xv0) ? 1.f : 0.f);
    float w11 = wy * wx * ((yv1 && xv1) ? 1.f : 0.f);
    int xc0 = min(max(x0, 0), HW - 1), xc1 = min(max(x0 + 1, 0), HW - 1);
    int yc0 = min(max(y0, 0), HW - 1), yc1 = min(max(y0 + 1, 0), HW - 1);
    const float* fb = feat + (size_t)b * 96 * HWHW + (size_t)cg * 24 * HWHW;
    int i00 = yc0 * HW + xc0, i01 = yc0 * HW + xc1;
    int i10 = yc1 * HW + xc0, i11 = yc1 * HW + xc1;
#pragma unroll
    for (int c = 0; c < 24; c += 8) {
        float r[8];
#pragma unroll
        for (int j = 0; j < 8; ++j) {
            const float* fc = fb + (size_t)(c + j) * HWHW;
            r[j] = w00 * fc[i00] + w01 * fc[i01] + w10 * fc[i10] + w11 * fc[i11];
        }
        uint4 u;
        u.x = pack_bf2(r[0], r[1]);
        u.y = pack_bf2(r[2], r[3]);
        u.z = pack_bf2(r[4], r[5]);
        u.w = pack_bf2(r[6], r[7]);
        s_t[t * 3 + (c >> 3)] = u;
    }
    __syncthreads();
    uint4* ob = (uint4*)(out + (size_t)blk * 64 * 96);
    ob[t] = s_t[t];
    ob[t + 256] = s_t[t + 256];
    ob[t + 512] = s_t[t + 512];
}

// ---------------- correlation via banded-Gram MFMA ----------------
#define CIS2 40  // halfword stride per px: 80B => 16B-aligned b128, ~2-way banks (free)
__global__ __launch_bounds__(256) void corr_mfma_kernel(const float* __restrict__ f1,
                                                        const __hip_bfloat16* __restrict__ f2,
                                                        __hip_bfloat16* __restrict__ out) {
    __shared__ __hip_bfloat16 s_f1h[4 * 16 * CIS2];
    __shared__ __hip_bfloat16 s_f1l[4 * 16 * CIS2];
    __shared__ __hip_bfloat16 s_f2[10 * 22 * CIS2];
    __shared__ float s_out[4][16][52];

    const int t = threadIdx.x;
    const int lane = t & 63;
    const int wave = t >> 6;   // y-row within block
    const int q = lane >> 4;
    const int l16 = lane & 15;
    const int x0 = blockIdx.x * 16;
    const int y0 = blockIdx.y * 4;
    const int b = blockIdx.z;

    floatx4 acc[7][2];
#pragma unroll
    for (int d = 0; d < 7; ++d)
#pragma unroll
        for (int nt = 0; nt < 2; ++nt) acc[d][nt] = (floatx4){0.f, 0.f, 0.f, 0.f};

    for (int ci0 = 0; ci0 < 96; ci0 += 32) {
        __syncthreads();
        // stage f1: 4 rows x 16 px x 32 ch, NCHW fp32 -> bf16 hi + lo residual, [row][px][ci]
        for (int idx = t; idx < 1024; idx += 256) {
            int px = idx & 15;
            int cp = (idx >> 4) & 15;   // channel pair
            int row = idx >> 8;
            const float* p = f1 + (size_t)(b * 96 + ci0 + cp * 2) * HWHW + (y0 + row) * HW + (x0 + px);
            float v0 = p[0], v1 = p[HWHW];
            float h0 = __bfloat162float(__float2bfloat16(v0));
            float h1 = __bfloat162float(__float2bfloat16(v1));
            int o = (row * 16 + px) * CIS2 + cp * 2;
            *(unsigned*)&s_f1h[o] = pack_bf2(v0, v1);
            *(unsigned*)&s_f1l[o] = pack_bf2(v0 - h0, v1 - h1);
        }
        // stage f2 slab: rows y0-3..y0+6 (10), cols x0-3..x0+18 (22), 32 ch, zero-fill OOB
        for (int idx = t; idx < 10 * 22 * 4; idx += 256) {
            int c16 = idx & 3;
            int c = (idx >> 2) % 22;
            int rr = idx / 88;
            int gy = y0 + rr - 3, gx = x0 + c - 3;
            uint4 u = make_uint4(0u, 0u, 0u, 0u);
            if ((unsigned)gy < (unsigned)HW && (unsigned)gx < (unsigned)HW)
                u = *(const uint4*)&f2[(size_t)((b * HW + gy) * HW + gx) * 96 + ci0 + c16 * 8];
            *(uint4*)&s_f2[(rr * 22 + c) * CIS2 + c16 * 8] = u;
        }
        __syncthreads();
        short8 Ah = *(const short8*)&s_f1h[(wave * 16 + l16) * CIS2 + q * 8];
        short8 Al = *(const short8*)&s_f1l[(wave * 16 + l16) * CIS2 + q * 8];
#pragma unroll
        for (int d = 0; d < 7; ++d) {
#pragma unroll
            for (int nt = 0; nt < 2; ++nt) {
                int col = nt * 16 + l16;
                col = col < 22 ? col : 21;  // lanes past the band read col 21 (discarded)
                short8 B = *(const short8*)&s_f2[((wave + d) * 22 + col) * CIS2 + q * 8];
                acc[d][nt] = __builtin_amdgcn_mfma_f32_16x16x32_bf16(Ah, B, acc[d][nt], 0, 0, 0);
                acc[d][nt] = __builtin_amdgcn_mfma_f32_16x16x32_bf16(Al, B, acc[d][nt], 0, 0, 0);
            }
        }
    }
    // extract band: D row (q*4+reg) = f1 px, col (nt*16+l16) = f2 col; dx = col-row
#pragma unroll
    for (int d = 0; d < 7; ++d)
#pragma unroll
        for (int nt = 0; nt < 2; ++nt)
#pragma unroll
            for (int reg = 0; reg < 4; ++reg) {
                int p1 = q * 4 + reg;
                int dx = nt * 16 + l16 - p1;
                if (dx >= 0 && dx < 7) s_out[wave][p1][d * 7 + dx] = acc[d][nt][reg];
            }
    __syncthreads();
    // coalesced NHWC64 bf16 write: /96 + leaky, ch 49..63 zero
    {
        int px = t >> 2;
        int row = px >> 4, xl = px & 15;
        int ch0 = (t & 3) * 16;
        int gy = y0 + row, gx = x0 + xl;
        float r[16];
#pragma unroll
        for (int j = 0; j < 16; ++j) {
            int ch = ch0 + j;
            float a = (ch < 49) ? s_out[row][xl][ch] * (1.0f / 96.0f) : 0.f;
            r[j] = a >= 0.f ? a : 0.1f * a;
        }
        __hip_bfloat16* op = out + (size_t)((b * HW + gy) * HW + gx) * 64 + ch0;
        uint4 u0, u1;
        u0.x = pack_bf2(r[0], r[1]);  u0.y = pack_bf2(r[2], r[3]);
        u0.z = pack_bf2(r[4], r[5]);  u0.w = pack_bf2(r[6], r[7]);
        u1.x = pack_bf2(r[8], r[9]);  u1.y = pack_bf2(r[10], r[11]);
        u1.z = pack_bf2(r[12], r[13]); u1.w = pack_bf2(r[14], r[15]);
        *(uint4*)op = u0;
        *(uint4*)(op + 8) = u1;
    }
}

// ---------------- MFMA implicit-GEMM 3x3 conv (m97-style 4x4 wave tile) ----------------
template <int CIN, int COUT, int WAVES_CO, int WCO, int LEAKY>
__global__ __launch_bounds__(256) void convk(const __hip_bfloat16* __restrict__ in,
                                             const __hip_bfloat16* __restrict__ wg,
                                             const float* __restrict__ bias,
                                             __hip_bfloat16* __restrict__ out) {
    constexpr int WAVES_PX = 4 / WAVES_CO;
    constexpr int BR = WAVES_PX * 4;          // block rows of pixels
    constexpr int CIS = 36;                   // padded ci stride (72B -> 16-bank spread)
    static_assert(WAVES_CO * WCO * 16 == COUT, "one co-block covers all COUT");
    __shared__ __hip_bfloat16 s_in[BR * 18 * CIS];
    __shared__ __hip_bfloat16 s_w[3 * COUT * CIS];

    const int t = threadIdx.x;
    const int lane = t & 63;
    const int wave = t >> 6;
    const int q = lane >> 4;
    const int l16 = lane & 15;
    const int wr = wave % WAVES_PX;           // px row-group
    const int wc = wave / WAVES_PX;           // co group
    const int x0 = blockIdx.x * 16;
    const int y0 = blockIdx.y * BR;
    const int b = blockIdx.z;

    floatx4 acc[4][WCO];
#pragma unroll
    for (int i = 0; i < 4; ++i)
#pragma unroll
        for (int j = 0; j < WCO; ++j) acc[i][j] = (floatx4){0.f, 0.f, 0.f, 0.f};

    for (int ci0 = 0; ci0 < CIN; ci0 += 32) {
#pragma unroll
        for (int ky = 0; ky < 3; ++ky) {
            __syncthreads();
            // stage input rows [y0+ky-1 .. +BR-1], cols [x0-1 .. x0+16], 32 ci
            for (int ch = t; ch < BR * 18 * 4; ch += 256) {
                int c8 = (ch & 3) * 8;
                int px = ch >> 2;
                int s = px / 18, cc = px % 18;
                int gy = y0 + s + ky - 1, gx = x0 + cc - 1;
                uint4 u = make_uint4(0u, 0u, 0u, 0u);
                if ((unsigned)gy < (unsigned)HW && (unsigned)gx < (unsigned)HW)
                    u = *(const uint4*)&in[(size_t)((b * HW + gy) * HW + gx) * CIN + ci0 + c8];
                *(uint4*)&s_in[(s * 18 + cc) * CIS + c8] = u;
            }
            // stage weights [kx 0..2][COUT][32ci]
            for (int ch = t; ch < 3 * COUT * 4; ch += 256) {
                int c8 = (ch & 3) * 8;
                int co = (ch >> 2) % COUT;
                int kx = ch / (COUT * 4);
                *(uint4*)&s_w[(kx * COUT + co) * CIS + c8] =
                    *(const uint4*)&wg[(size_t)((ky * 3 + kx) * COUT + co) * CIN + ci0 + c8];
            }
            __syncthreads();
#pragma unroll
            for (int kx = 0; kx < 3; ++kx) {
                short8 A[WCO], B[4];
#pragma unroll
                for (int ct = 0; ct < WCO; ++ct)
                    A[ct] = *(const short8*)&s_w[(kx * COUT + wc * WCO * 16 + ct * 16 + l16) * CIS + q * 8];
#pragma unroll
                for (int pt = 0; pt < 4; ++pt)
                    B[pt] = *(const short8*)&s_in[((wr * 4 + pt) * 18 + l16 + kx) * CIS + q * 8];
#pragma unroll
                for (int pt = 0; pt < 4; ++pt)
#pragma unroll
                    for (int ct = 0; ct < WCO; ++ct)
                        acc[pt][ct] = __builtin_amdgcn_mfma_f32_16x16x32_bf16(A[ct], B[pt], acc[pt][ct], 0, 0, 0);
            }
        }
    }
    // epilogue: D col(lane&15)=pixel col, row(q*4+reg)=co within tile
#pragma unroll
    for (int pt = 0; pt < 4; ++pt) {
        int y = y0 + wr * 4 + pt;
        int x = x0 + l16;
        size_t pixbase = (size_t)((b * HW + y) * HW + x) * COUT;
#pragma unroll
        for (int ct = 0; ct < WCO; ++ct) {
            int co4 = wc * WCO * 16 + ct * 16 + q * 4;
            float4 bv = *(const float4*)&bias[co4];
            float r[4];
#pragma unroll
            for (int reg = 0; reg < 4; ++reg) {
                float vv = acc[pt][ct][reg] + ((const float*)&bv)[reg];
                if (LEAKY) vv = vv >= 0.f ? vv : 0.1f * vv;
                r[reg] = vv;
            }
            uint2 u;
            u.x = pack_bf2(r[0], r[1]);
            u.y = pack_bf2(r[2], r[3]);
            *(uint2*)&out[pixbase + co4] = u;
        }
    }
}

// ---------------- conv4: 5x5, 32->2, pad 2, NHWC32 bf16 in, + bias + flow residual ----------------
__global__ __launch_bounds__(256) void conv4_kernel(const __hip_bfloat16* __restrict__ in,
                                                    const float* __restrict__ wg,
                                                    const float* __restrict__ bias,
                                                    const float* __restrict__ flow,
                                                    float* __restrict__ out) {
    __shared__ float s_in[20 * 20 * 36];
    __shared__ float s_w[2 * 25 * 32];
    int t = threadIdx.x;
    int tx = t % 16, ty = t / 16;
    int x0 = blockIdx.x * 16, y0 = blockIdx.y * 16, b = blockIdx.z;
    for (int ch = t; ch < 400 * 4; ch += 256) {
        int px = ch >> 2;
        int c8 = (ch & 3) * 8;
        int ry = px / 20, rx = px % 20;
        int gy = y0 + ry - 2, gx = x0 + rx - 2;
        float4 lo = make_float4(0.f, 0.f, 0.f, 0.f), hi = lo;
        if ((unsigned)gy < (unsigned)HW && (unsigned)gx < (unsigned)HW) {
            const __hip_bfloat16* p = &in[(size_t)((b * HW + gy) * HW + gx) * 32 + c8];
            lo = ld_bf16x4(p);
            hi = ld_bf16x4(p + 4);
        }
        *(float4*)&s_in[px * 36 + c8] = lo;
        *(float4*)&s_in[px * 36 + c8 + 4] = hi;
    }
    for (int p = t; p < 1600; p += 256) {
        int ci = p % 32;
        int k = (p / 32) % 25;
        int co = p / 800;
        s_w[(co * 25 + k) * 32 + ci] = wg[(co * 32 + ci) * 25 + k];
    }
    __syncthreads();
    float acc0 = 0.f, acc1 = 0.f;
#pragma unroll
    for (int ky = 0; ky < 5; ++ky) {
#pragma unroll
        for (int kx = 0; kx < 5; ++kx) {
            int k = ky * 5 + kx;
            int base = ((ty + ky) * 20 + tx + kx) * 36;
#pragma unroll
            for (int c4 = 0; c4 < 32; c4 += 4) {
                float4 v = *(const float4*)&s_in[base + c4];
                float4 w0 = *(const float4*)&s_w[(0 * 25 + k) * 32 + c4];
                float4 w1 = *(const float4*)&s_w[(1 * 25 + k) * 32 + c4];
                acc0 += v.x * w0.x + v.y * w0.y + v.z * w0.z + v.w * w0.w;
                acc1 += v.x * w1.x + v.y * w1.y + v.z * w1.z + v.w * w1.w;
            }
        }
    }
    int gy = y0 + ty, gx = x0 + tx;
    int o0 = ((b * 2 + 0) * HWHW) + gy * HW + gx;
    int o1 = ((b * 2 + 1) * HWHW) + gy * HW + gx;
    out[o0] = acc0 + bias[0] + flow[o0];
    out[o1] = acc1 + bias[1] + flow[o1];
}

extern "C" void kernel_launch(void* const* d_in, const int* in_sizes, int n_in,
                              void* d_out, int out_size, void* d_ws, size_t ws_size,
                              hipStream_t stream) {
    (void)in_sizes; (void)n_in; (void)out_size; (void)ws_size;
    const float* f1      = (const float*)d_in[2];
    const float* f2in    = (const float*)d_in[3];
    const float* flow_in = (const float*)d_in[4];
    const float* w_up    = (const float*)d_in[5];
    const float* w1      = (const float*)d_in[6];
    const float* b1      = (const float*)d_in[7];
    const float* w2      = (const float*)d_in[8];
    const float* b2      = (const float*)d_in[9];
    const float* w3      = (const float*)d_in[10];
    const float* b3      = (const float*)d_in[11];
    const float* w4      = (const float*)d_in[12];
    const float* b4      = (const float*)d_in[13];
    float* out = (float*)d_out;
    char* ws = (char*)d_ws;

    // ws layout: flow fp32 [0,1179648) | w1b [1179648) | w2b [1327104) | w3b [1474560)
    //   R1 (feat2 NHWC96 / x1 NHWC128) [1511424, +37748736)
    //   R2 (corr/x2 NHWC64) [39260160, +18874368) | R3 (x3 NHWC32) [58134528, +9437184)
    float* flow = (float*)ws;
    __hip_bfloat16* w1b = (__hip_bfloat16*)(ws + 1179648);
    __hip_bfloat16* w2b = (__hip_bfloat16*)(ws + 1327104);
    __hip_bfloat16* w3b = (__hip_bfloat16*)(ws + 1474560);
    __hip_bfloat16* R1  = (__hip_bfloat16*)(ws + 1511424);
    __hip_bfloat16* R2  = (__hip_bfloat16*)(ws + 39260160);
    __hip_bfloat16* R3  = (__hip_bfloat16*)(ws + 58134528);

    upflow_kernel<<<1152, 256, 0, stream>>>(flow_in, w_up, flow);
    wprep_kernel<<<288, 256, 0, stream>>>(w1, w1b, 128, 49, 64);
    wprep_kernel<<<288, 256, 0, stream>>>(w2, w2b, 64, 128, 128);
    wprep_kernel<<<72, 256, 0, stream>>>(w3, w3b, 32, 64, 64);
    backwarp_kernel<<<2304, 256, 0, stream>>>(f2in, flow, R1);
    corr_mfma_kernel<<<dim3(12, 48, NB), 256, 0, stream>>>(f1, R1, R2);
    convk<64, 128, 2, 4, 1><<<dim3(12, 24, NB), 256, 0, stream>>>(R2, w1b, b1, R1);
    convk<128, 64, 1, 4, 1><<<dim3(12, 12, NB), 256, 0, stream>>>(R1, w2b, b2, R2);
    convk<64, 32, 1, 2, 1><<<dim3(12, 12, NB), 256, 0, stream>>>(R2, w3b, b3, R3);
    conv4_kernel<<<dim3(12, 12, NB), 256, 0, stream>>>(R3, w4, b4, flow, out);
}

// Round 4
// 491.324 us; speedup vs baseline: 1.2023x; 1.0612x over previous
//
#include <hip/hip_runtime.h>
#include <hip/hip_bf16.h>

#define HW 192
#define HWHW 36864
#define NB 4

typedef __attribute__((ext_vector_type(8))) short short8;
typedef __attribute__((ext_vector_type(4))) float floatx4;

__device__ __forceinline__ unsigned pack_bf2(float a, float b) {
    __hip_bfloat162 h = __float22bfloat162_rn(make_float2(a, b));
    return *(unsigned*)&h;
}
__device__ __forceinline__ float4 ld_bf16x4(const __hip_bfloat16* p) {
    uint2 u = *(const uint2*)p;
    __hip_bfloat162 a = *(__hip_bfloat162*)&u.x;
    __hip_bfloat162 b = *(__hip_bfloat162*)&u.y;
    float2 fa = __bfloat1622float2(a), fb = __bfloat1622float2(b);
    return make_float4(fa.x, fa.y, fb.x, fb.y);
}
__device__ __forceinline__ void st_bf16x4(__hip_bfloat16* p, float4 v) {
    uint2 u;
    u.x = pack_bf2(v.x, v.y);
    u.y = pack_bf2(v.z, v.w);
    *(uint2*)p = u;
}

// ---------------- upflow ----------------
__global__ void upflow_kernel(const float* __restrict__ fin,
                              const float* __restrict__ w,
                              float* __restrict__ fout) {
    int idx = blockIdx.x * blockDim.x + threadIdx.x;
    if (idx >= NB * 2 * HWHW) return;
    int x = idx % HW;
    int y = (idx / HW) % HW;
    int g = (idx / HWHW) % 2;
    int b = idx / (2 * HWHW);
    float acc = 0.f;
#pragma unroll
    for (int ky = 0; ky < 4; ++ky) {
        int py = y + ky - 2;
        if (py < 0 || py > 190 || (py & 1)) continue;
        int iy = py >> 1;
#pragma unroll
        for (int kx = 0; kx < 4; ++kx) {
            int px = x + kx - 2;
            if (px < 0 || px > 190 || (px & 1)) continue;
            int ix = px >> 1;
            acc += fin[((b * 2 + g) * 96 + iy) * 96 + ix] *
                   w[g * 16 + (3 - ky) * 4 + (3 - kx)];
        }
    }
    fout[idx] = acc;
}

// ---------------- weight prep: fp32 [CO][CI][3][3] -> bf16 [9][CO][CIP] ----------------
__global__ void wprep_kernel(const float* __restrict__ w, __hip_bfloat16* __restrict__ out,
                             int CO, int CI, int CIP) {
    int idx = blockIdx.x * blockDim.x + threadIdx.x;
    int n = 9 * CO * CIP;
    if (idx >= n) return;
    int ci = idx % CIP;
    int co = (idx / CIP) % CO;
    int k9 = idx / (CIP * CO);
    float v = (ci < CI) ? w[(co * CI + ci) * 9 + k9] : 0.f;
    out[idx] = __float2bfloat16(v);
}

// ---------------- channel-oct repack: feat NCHW fp32 -> [b][c/8][y][x][8] fp16 ----------------
// Pure streaming, both sides coalesced. Gives the gather kernel 16B/address granularity.
__global__ __launch_bounds__(256) void coct_kernel(const float* __restrict__ feat,
                                                   _Float16* __restrict__ out) {
    int idx = blockIdx.x * 256 + threadIdx.x;   // (b*12 + oc)*HWHW + i
    int i = idx % HWHW;
    int oc = (idx / HWHW) % 12;
    int b = idx / (12 * HWHW);
    const float* f = feat + ((size_t)(b * 96 + oc * 8)) * HWHW + i;
    _Float16 v[8];
#pragma unroll
    for (int j = 0; j < 8; ++j) v[j] = (_Float16)f[(size_t)j * HWHW];
    *(uint4*)&out[(size_t)idx * 8] = *(uint4*)v;
}

// ---------------- backwarp: oct-gather (12 x 16B loads/thread) + XCD swizzle + LDS writeback ----
// lane = (pixel, cg); cg covers 24 ch = 3 octs. Bilinear corners read as fp16 octs
// (16B per address -> 8x fewer L1 line-probes than NCHW dword gathers), lerp in fp32.
__global__ __launch_bounds__(256) void backwarp_kernel(const _Float16* __restrict__ foct,
                                                       const float* __restrict__ flow,
                                                       __hip_bfloat16* __restrict__ out) {
    __shared__ uint4 s_t[768];
    int bid = blockIdx.x;
    int blk = (bid & 7) * 288 + (bid >> 3);   // 2304 blocks, 288 per XCD, bijective
    int t = threadIdx.x;
    int cg = t & 3;
    int pl = t >> 2;                           // local pixel 0..63
    int p = blk * 64 + pl;
    int x = p % HW;
    int y = (p / HW) % HW;
    int b = p / HWHW;
    float fx = flow[((b * 2 + 0) * HW + y) * HW + x] * 2.5f;
    float fy = flow[((b * 2 + 1) * HW + y) * HW + x] * 2.5f;
    float gx = (float)x + fx, gy = (float)y + fy;
    float x0f = floorf(gx), y0f = floorf(gy);
    float wx = gx - x0f, wy = gy - y0f;
    int x0 = (int)x0f, y0 = (int)y0f;
    bool xv0 = (unsigned)x0 < (unsigned)HW;
    bool xv1 = (unsigned)(x0 + 1) < (unsigned)HW;
    bool yv0 = (unsigned)y0 < (unsigned)HW;
    bool yv1 = (unsigned)(y0 + 1) < (unsigned)HW;
    float w00 = (1.f - wy) * (1.f - wx) * ((yv0 && xv0) ? 1.f : 0.f);
    float w01 = (1.f - wy) * wx * ((yv0 && xv1) ? 1.f : 0.f);
    float w10 = wy * (1.f - wx) * ((yv1 && xv0) ? 1.f : 0.f);
    float w11 = wy * wx * ((yv1 && xv1) ? 1.f : 0.f);
    int xc0 = min(max(x0, 0), HW - 1), xc1 = min(max(x0 + 1, 0), HW - 1);
    int yc0 = min(max(y0, 0), HW - 1), yc1 = min(max(y0 + 1, 0), HW - 1);
    int i00 = yc0 * HW + xc0, i01 = yc0 * HW + xc1;
    int i10 = yc1 * HW + xc0, i11 = yc1 * HW + xc1;
    const _Float16* fo = foct + (size_t)(b * 12 + cg * 3) * HWHW * 8;
#pragma unroll
    for (int k = 0; k < 3; ++k) {
        const _Float16* fk = fo + (size_t)k * HWHW * 8;
        uint4 u00 = *(const uint4*)&fk[(size_t)i00 * 8];
        uint4 u01 = *(const uint4*)&fk[(size_t)i01 * 8];
        uint4 u10 = *(const uint4*)&fk[(size_t)i10 * 8];
        uint4 u11 = *(const uint4*)&fk[(size_t)i11 * 8];
        const _Float16* h00 = (const _Float16*)&u00;
        const _Float16* h01 = (const _Float16*)&u01;
        const _Float16* h10 = (const _Float16*)&u10;
        const _Float16* h11 = (const _Float16*)&u11;
        float r[8];
#pragma unroll
        for (int j = 0; j < 8; ++j)
            r[j] = w00 * (float)h00[j] + w01 * (float)h01[j] +
                   w10 * (float)h10[j] + w11 * (float)h11[j];
        uint4 u;
        u.x = pack_bf2(r[0], r[1]);
        u.y = pack_bf2(r[2], r[3]);
        u.z = pack_bf2(r[4], r[5]);
        u.w = pack_bf2(r[6], r[7]);
        s_t[t * 3 + k] = u;
    }
    __syncthreads();
    uint4* ob = (uint4*)(out + (size_t)blk * 64 * 96);
    ob[t] = s_t[t];
    ob[t + 256] = s_t[t + 256];
    ob[t + 512] = s_t[t + 512];
}

// ---------------- correlation via banded-Gram MFMA ----------------
#define CIS2 40  // halfword stride per px: 80B => 16B-aligned b128, ~2-way banks (free)
__global__ __launch_bounds__(256) void corr_mfma_kernel(const float* __restrict__ f1,
                                                        const __hip_bfloat16* __restrict__ f2,
                                                        __hip_bfloat16* __restrict__ out) {
    __shared__ __hip_bfloat16 s_f1h[4 * 16 * CIS2];
    __shared__ __hip_bfloat16 s_f1l[4 * 16 * CIS2];
    __shared__ __hip_bfloat16 s_f2[10 * 22 * CIS2];
    __shared__ float s_out[4][16][52];

    const int t = threadIdx.x;
    const int lane = t & 63;
    const int wave = t >> 6;   // y-row within block
    const int q = lane >> 4;
    const int l16 = lane & 15;
    const int x0 = blockIdx.x * 16;
    const int y0 = blockIdx.y * 4;
    const int b = blockIdx.z;

    floatx4 acc[7][2];
#pragma unroll
    for (int d = 0; d < 7; ++d)
#pragma unroll
        for (int nt = 0; nt < 2; ++nt) acc[d][nt] = (floatx4){0.f, 0.f, 0.f, 0.f};

    for (int ci0 = 0; ci0 < 96; ci0 += 32) {
        __syncthreads();
        // stage f1: 4 rows x 16 px x 32 ch, NCHW fp32 -> bf16 hi + lo residual, [row][px][ci]
        for (int idx = t; idx < 1024; idx += 256) {
            int px = idx & 15;
            int cp = (idx >> 4) & 15;   // channel pair
            int row = idx >> 8;
            const float* p = f1 + (size_t)(b * 96 + ci0 + cp * 2) * HWHW + (y0 + row) * HW + (x0 + px);
            float v0 = p[0], v1 = p[HWHW];
            float h0 = __bfloat162float(__float2bfloat16(v0));
            float h1 = __bfloat162float(__float2bfloat16(v1));
            int o = (row * 16 + px) * CIS2 + cp * 2;
            *(unsigned*)&s_f1h[o] = pack_bf2(v0, v1);
            *(unsigned*)&s_f1l[o] = pack_bf2(v0 - h0, v1 - h1);
        }
        // stage f2 slab: rows y0-3..y0+6 (10), cols x0-3..x0+18 (22), 32 ch, zero-fill OOB
        for (int idx = t; idx < 10 * 22 * 4; idx += 256) {
            int c16 = idx & 3;
            int c = (idx >> 2) % 22;
            int rr = idx / 88;
            int gy = y0 + rr - 3, gx = x0 + c - 3;
            uint4 u = make_uint4(0u, 0u, 0u, 0u);
            if ((unsigned)gy < (unsigned)HW && (unsigned)gx < (unsigned)HW)
                u = *(const uint4*)&f2[(size_t)((b * HW + gy) * HW + gx) * 96 + ci0 + c16 * 8];
            *(uint4*)&s_f2[(rr * 22 + c) * CIS2 + c16 * 8] = u;
        }
        __syncthreads();
        short8 Ah = *(const short8*)&s_f1h[(wave * 16 + l16) * CIS2 + q * 8];
        short8 Al = *(const short8*)&s_f1l[(wave * 16 + l16) * CIS2 + q * 8];
#pragma unroll
        for (int d = 0; d < 7; ++d) {
#pragma unroll
            for (int nt = 0; nt < 2; ++nt) {
                int col = nt * 16 + l16;
                col = col < 22 ? col : 21;  // lanes past the band read col 21 (discarded)
                short8 B = *(const short8*)&s_f2[((wave + d) * 22 + col) * CIS2 + q * 8];
                acc[d][nt] = __builtin_amdgcn_mfma_f32_16x16x32_bf16(Ah, B, acc[d][nt], 0, 0, 0);
                acc[d][nt] = __builtin_amdgcn_mfma_f32_16x16x32_bf16(Al, B, acc[d][nt], 0, 0, 0);
            }
        }
    }
    // extract band: D row (q*4+reg) = f1 px, col (nt*16+l16) = f2 col; dx = col-row
#pragma unroll
    for (int d = 0; d < 7; ++d)
#pragma unroll
        for (int nt = 0; nt < 2; ++nt)
#pragma unroll
            for (int reg = 0; reg < 4; ++reg) {
                int p1 = q * 4 + reg;
                int dx = nt * 16 + l16 - p1;
                if (dx >= 0 && dx < 7) s_out[wave][p1][d * 7 + dx] = acc[d][nt][reg];
            }
    __syncthreads();
    // coalesced NHWC64 bf16 write: /96 + leaky, ch 49..63 zero
    {
        int px = t >> 2;
        int row = px >> 4, xl = px & 15;
        int ch0 = (t & 3) * 16;
        int gy = y0 + row, gx = x0 + xl;
        float r[16];
#pragma unroll
        for (int j = 0; j < 16; ++j) {
            int ch = ch0 + j;
            float a = (ch < 49) ? s_out[row][xl][ch] * (1.0f / 96.0f) : 0.f;
            r[j] = a >= 0.f ? a : 0.1f * a;
        }
        __hip_bfloat16* op = out + (size_t)((b * HW + gy) * HW + gx) * 64 + ch0;
        uint4 u0, u1;
        u0.x = pack_bf2(r[0], r[1]);  u0.y = pack_bf2(r[2], r[3]);
        u0.z = pack_bf2(r[4], r[5]);  u0.w = pack_bf2(r[6], r[7]);
        u1.x = pack_bf2(r[8], r[9]);  u1.y = pack_bf2(r[10], r[11]);
        u1.z = pack_bf2(r[12], r[13]); u1.w = pack_bf2(r[14], r[15]);
        *(uint4*)op = u0;
        *(uint4*)(op + 8) = u1;
    }
}

// ---------------- MFMA implicit-GEMM 3x3 conv (m97-style 4x4 wave tile) ----------------
template <int CIN, int COUT, int WAVES_CO, int WCO, int LEAKY>
__global__ __launch_bounds__(256) void convk(const __hip_bfloat16* __restrict__ in,
                                             const __hip_bfloat16* __restrict__ wg,
                                             const float* __restrict__ bias,
                                             __hip_bfloat16* __restrict__ out) {
    constexpr int WAVES_PX = 4 / WAVES_CO;
    constexpr int BR = WAVES_PX * 4;          // block rows of pixels
    constexpr int CIS = 36;                   // padded ci stride (72B -> 16-bank spread)
    static_assert(WAVES_CO * WCO * 16 == COUT, "one co-block covers all COUT");
    __shared__ __hip_bfloat16 s_in[BR * 18 * CIS];
    __shared__ __hip_bfloat16 s_w[3 * COUT * CIS];

    const int t = threadIdx.x;
    const int lane = t & 63;
    const int wave = t >> 6;
    const int q = lane >> 4;
    const int l16 = lane & 15;
    const int wr = wave % WAVES_PX;           // px row-group
    const int wc = wave / WAVES_PX;           // co group
    const int x0 = blockIdx.x * 16;
    const int y0 = blockIdx.y * BR;
    const int b = blockIdx.z;

    floatx4 acc[4][WCO];
#pragma unroll
    for (int i = 0; i < 4; ++i)
#pragma unroll
        for (int j = 0; j < WCO; ++j) acc[i][j] = (floatx4){0.f, 0.f, 0.f, 0.f};

    for (int ci0 = 0; ci0 < CIN; ci0 += 32) {
#pragma unroll
        for (int ky = 0; ky < 3; ++ky) {
            __syncthreads();
            // stage input rows [y0+ky-1 .. +BR-1], cols [x0-1 .. x0+16], 32 ci
            for (int ch = t; ch < BR * 18 * 4; ch += 256) {
                int c8 = (ch & 3) * 8;
                int px = ch >> 2;
                int s = px / 18, cc = px % 18;
                int gy = y0 + s + ky - 1, gx = x0 + cc - 1;
                uint4 u = make_uint4(0u, 0u, 0u, 0u);
                if ((unsigned)gy < (unsigned)HW && (unsigned)gx < (unsigned)HW)
                    u = *(const uint4*)&in[(size_t)((b * HW + gy) * HW + gx) * CIN + ci0 + c8];
                *(uint4*)&s_in[(s * 18 + cc) * CIS + c8] = u;
            }
            // stage weights [kx 0..2][COUT][32ci]
            for (int ch = t; ch < 3 * COUT * 4; ch += 256) {
                int c8 = (ch & 3) * 8;
                int co = (ch >> 2) % COUT;
                int kx = ch / (COUT * 4);
                *(uint4*)&s_w[(kx * COUT + co) * CIS + c8] =
                    *(const uint4*)&wg[(size_t)((ky * 3 + kx) * COUT + co) * CIN + ci0 + c8];
            }
            __syncthreads();
#pragma unroll
            for (int kx = 0; kx < 3; ++kx) {
                short8 A[WCO], B[4];
#pragma unroll
                for (int ct = 0; ct < WCO; ++ct)
                    A[ct] = *(const short8*)&s_w[(kx * COUT + wc * WCO * 16 + ct * 16 + l16) * CIS + q * 8];
#pragma unroll
                for (int pt = 0; pt < 4; ++pt)
                    B[pt] = *(const short8*)&s_in[((wr * 4 + pt) * 18 + l16 + kx) * CIS + q * 8];
#pragma unroll
                for (int pt = 0; pt < 4; ++pt)
#pragma unroll
                    for (int ct = 0; ct < WCO; ++ct)
                        acc[pt][ct] = __builtin_amdgcn_mfma_f32_16x16x32_bf16(A[ct], B[pt], acc[pt][ct], 0, 0, 0);
            }
        }
    }
    // epilogue: D col(lane&15)=pixel col, row(q*4+reg)=co within tile
#pragma unroll
    for (int pt = 0; pt < 4; ++pt) {
        int y = y0 + wr * 4 + pt;
        int x = x0 + l16;
        size_t pixbase = (size_t)((b * HW + y) * HW + x) * COUT;
#pragma unroll
        for (int ct = 0; ct < WCO; ++ct) {
            int co4 = wc * WCO * 16 + ct * 16 + q * 4;
            float4 bv = *(const float4*)&bias[co4];
            float r[4];
#pragma unroll
            for (int reg = 0; reg < 4; ++reg) {
                float vv = acc[pt][ct][reg] + ((const float*)&bv)[reg];
                if (LEAKY) vv = vv >= 0.f ? vv : 0.1f * vv;
                r[reg] = vv;
            }
            uint2 u;
            u.x = pack_bf2(r[0], r[1]);
            u.y = pack_bf2(r[2], r[3]);
            *(uint2*)&out[pixbase + co4] = u;
        }
    }
}

// ---------------- conv4: 5x5, 32->2, pad 2, NHWC32 bf16 in, + bias + flow residual ----------------
__global__ __launch_bounds__(256) void conv4_kernel(const __hip_bfloat16* __restrict__ in,
                                                    const float* __restrict__ wg,
                                                    const float* __restrict__ bias,
                                                    const float* __restrict__ flow,
                                                    float* __restrict__ out) {
    __shared__ float s_in[20 * 20 * 36];
    __shared__ float s_w[2 * 25 * 32];
    int t = threadIdx.x;
    int tx = t % 16, ty = t / 16;
    int x0 = blockIdx.x * 16, y0 = blockIdx.y * 16, b = blockIdx.z;
    for (int ch = t; ch < 400 * 4; ch += 256) {
        int px = ch >> 2;
        int c8 = (ch & 3) * 8;
        int ry = px / 20, rx = px % 20;
        int gy = y0 + ry - 2, gx = x0 + rx - 2;
        float4 lo = make_float4(0.f, 0.f, 0.f, 0.f), hi = lo;
        if ((unsigned)gy < (unsigned)HW && (unsigned)gx < (unsigned)HW) {
            const __hip_bfloat16* p = &in[(size_t)((b * HW + gy) * HW + gx) * 32 + c8];
            lo = ld_bf16x4(p);
            hi = ld_bf16x4(p + 4);
        }
        *(float4*)&s_in[px * 36 + c8] = lo;
        *(float4*)&s_in[px * 36 + c8 + 4] = hi;
    }
    for (int p = t; p < 1600; p += 256) {
        int ci = p % 32;
        int k = (p / 32) % 25;
        int co = p / 800;
        s_w[(co * 25 + k) * 32 + ci] = wg[(co * 32 + ci) * 25 + k];
    }
    __syncthreads();
    float acc0 = 0.f, acc1 = 0.f;
#pragma unroll
    for (int ky = 0; ky < 5; ++ky) {
#pragma unroll
        for (int kx = 0; kx < 5; ++kx) {
            int k = ky * 5 + kx;
            int base = ((ty + ky) * 20 + tx + kx) * 36;
#pragma unroll
            for (int c4 = 0; c4 < 32; c4 += 4) {
                float4 v = *(const float4*)&s_in[base + c4];
                float4 w0 = *(const float4*)&s_w[(0 * 25 + k) * 32 + c4];
                float4 w1 = *(const float4*)&s_w[(1 * 25 + k) * 32 + c4];
                acc0 += v.x * w0.x + v.y * w0.y + v.z * w0.z + v.w * w0.w;
                acc1 += v.x * w1.x + v.y * w1.y + v.z * w1.z + v.w * w1.w;
            }
        }
    }
    int gy = y0 + ty, gx = x0 + tx;
    int o0 = ((b * 2 + 0) * HWHW) + gy * HW + gx;
    int o1 = ((b * 2 + 1) * HWHW) + gy * HW + gx;
    out[o0] = acc0 + bias[0] + flow[o0];
    out[o1] = acc1 + bias[1] + flow[o1];
}

extern "C" void kernel_launch(void* const* d_in, const int* in_sizes, int n_in,
                              void* d_out, int out_size, void* d_ws, size_t ws_size,
                              hipStream_t stream) {
    (void)in_sizes; (void)n_in; (void)out_size; (void)ws_size;
    const float* f1      = (const float*)d_in[2];
    const float* f2in    = (const float*)d_in[3];
    const float* flow_in = (const float*)d_in[4];
    const float* w_up    = (const float*)d_in[5];
    const float* w1      = (const float*)d_in[6];
    const float* b1      = (const float*)d_in[7];
    const float* w2      = (const float*)d_in[8];
    const float* b2      = (const float*)d_in[9];
    const float* w3      = (const float*)d_in[10];
    const float* b3      = (const float*)d_in[11];
    const float* w4      = (const float*)d_in[12];
    const float* b4      = (const float*)d_in[13];
    float* out = (float*)d_out;
    char* ws = (char*)d_ws;

    // ws layout: flow fp32 [0,1179648) | w1b [1179648) | w2b [1327104) | w3b [1474560)
    //   R1 (feat2 NHWC96 / x1 NHWC128) [1511424, +37748736)
    //   R2 (corr/x2 NHWC64) [39260160, +18874368) | R3 (x3 NHWC32) [58134528, +9437184)
    //   oct buffer (fp16 c-oct repack of feat2) ALIASES R2+R3 [39260160, +28311552):
    //   written by coct_kernel, read by backwarp, dead before corr overwrites R2.
    float* flow = (float*)ws;
    __hip_bfloat16* w1b = (__hip_bfloat16*)(ws + 1179648);
    __hip_bfloat16* w2b = (__hip_bfloat16*)(ws + 1327104);
    __hip_bfloat16* w3b = (__hip_bfloat16*)(ws + 1474560);
    __hip_bfloat16* R1  = (__hip_bfloat16*)(ws + 1511424);
    __hip_bfloat16* R2  = (__hip_bfloat16*)(ws + 39260160);
    __hip_bfloat16* R3  = (__hip_bfloat16*)(ws + 58134528);
    _Float16* oct       = (_Float16*)(ws + 39260160);

    upflow_kernel<<<1152, 256, 0, stream>>>(flow_in, w_up, flow);
    coct_kernel<<<6912, 256, 0, stream>>>(f2in, oct);
    wprep_kernel<<<288, 256, 0, stream>>>(w1, w1b, 128, 49, 64);
    wprep_kernel<<<288, 256, 0, stream>>>(w2, w2b, 64, 128, 128);
    wprep_kernel<<<72, 256, 0, stream>>>(w3, w3b, 32, 64, 64);
    backwarp_kernel<<<2304, 256, 0, stream>>>(oct, flow, R1);
    corr_mfma_kernel<<<dim3(12, 48, NB), 256, 0, stream>>>(f1, R1, R2);
    convk<64, 128, 2, 4, 1><<<dim3(12, 24, NB), 256, 0, stream>>>(R2, w1b, b1, R1);
    convk<128, 64, 1, 4, 1><<<dim3(12, 12, NB), 256, 0, stream>>>(R1, w2b, b2, R2);
    convk<64, 32, 1, 2, 1><<<dim3(12, 12, NB), 256, 0, stream>>>(R2, w3b, b3, R3);
    conv4_kernel<<<dim3(12, 12, NB), 256, 0, stream>>>(R3, w4, b4, flow, out);
}